// Round 8
// baseline (454.571 us; speedup 1.0000x reference)
//
#include <hip/hip_runtime.h>
#include <hip/hip_bf16.h>
#include <cstdint>

// Problem constants
#define BB 4
#define SS 4096
#define DD 1024
#define MM (BB * SS)          // 16384 tokens
#define NTOT 4096             // 4 matrices * 1024 output features
#define BUDGET 2048

typedef __attribute__((ext_vector_type(8))) short short8v;   // 8 bf16 (4 VGPR)
typedef __attribute__((ext_vector_type(4))) float f32x4;

__device__ __forceinline__ float bf2f(unsigned int h) {
  return __uint_as_float(h << 16);
}
__device__ __forceinline__ unsigned short f2bf(float f) {
  unsigned int u = __float_as_uint(f);
  u = u + 0x7FFFu + ((u >> 16) & 1u);   // RNE
  return (unsigned short)(u >> 16);
}
__device__ __forceinline__ unsigned int pkbf(float lo, float hi) {
  float2 f; f.x = lo; f.y = hi;
  __hip_bfloat162 h = __float22bfloat162_rn(f);
  return *(unsigned int*)&h;
}

// ---------------- convert2: bf16 copies of x & W-concat + fused codebook probs ----
__global__ __launch_bounds__(256) void convert2_kernel(
    const float* __restrict__ x,
    const float* __restrict__ Wq, const float* __restrict__ Wk,
    const float* __restrict__ Wg, const float* __restrict__ Wm,
    const float* __restrict__ Wc,
    unsigned short* __restrict__ xb, unsigned short* __restrict__ Wb,
    float* __restrict__ probs)
{
  const int blk = blockIdx.x;
  const int t = threadIdx.x;
  if (blk < 4096) {
    const int wv = t >> 6, ln = t & 63;
    const int token = blk * 4 + wv;
    const size_t rowo = (size_t)token * DD;
    const float4* x4 = (const float4*)(x + rowo);
    const float4* Wc4 = (const float4*)Wc;
    float4 xv[4];
    #pragma unroll
    for (int e = 0; e < 4; ++e) xv[e] = x4[e * 64 + ln];
    uint2* xo = (uint2*)(xb + rowo);
    #pragma unroll
    for (int e = 0; e < 4; ++e) {
      uint2 o; o.x = pkbf(xv[e].x, xv[e].y); o.y = pkbf(xv[e].z, xv[e].w);
      xo[e * 64 + ln] = o;
    }
    float pj[16];
    #pragma unroll
    for (int j = 0; j < 16; ++j) {
      float a = 0.f;
      #pragma unroll
      for (int e = 0; e < 4; ++e) {
        const float4 w = Wc4[j * 256 + e * 64 + ln];
        a += xv[e].x * w.x + xv[e].y * w.y + xv[e].z * w.z + xv[e].w * w.w;
      }
      pj[j] = a;
    }
    #pragma unroll
    for (int j = 0; j < 16; ++j) {
      #pragma unroll
      for (int off = 1; off < 64; off <<= 1) pj[j] += __shfl_xor(pj[j], off);
    }
    if (ln == 0) {
      float p[16];
      float mx = -3.4e38f;
      #pragma unroll
      for (int j = 0; j < 16; ++j) { p[j] = pj[j] * 10.0f; mx = fmaxf(mx, p[j]); }
      float se = 0.f;
      #pragma unroll
      for (int j = 0; j < 16; ++j) { p[j] = expf(p[j] - mx); se += p[j]; }
      const float inv = 1.0f / se;
      #pragma unroll
      for (int j = 0; j < 16; ++j) p[j] *= inv;
      unsigned int mk = 0;
      for (int it = 0; it < 4; ++it) {
        int bi = 0; float bv = -1.f;
        #pragma unroll
        for (int j = 0; j < 16; ++j)
          if (!((mk >> j) & 1u) && p[j] > bv) { bv = p[j]; bi = j; }
        mk |= 1u << bi;
      }
      float ssum = 0.f;
      #pragma unroll
      for (int j = 0; j < 16; ++j) if ((mk >> j) & 1u) ssum += p[j];
      const float rinv = 1.0f / fmaxf(ssum, 1e-8f);
      #pragma unroll
      for (int j = 0; j < 16; ++j)
        probs[(size_t)token * 16 + j] = ((mk >> j) & 1u) ? p[j] * rinv : 0.f;
    }
  } else {
    const size_t off0 = (size_t)(blk - 4096) * 2048 + t * 8;
    const int m = (int)(off0 >> 20);
    const float* Ws = (m == 0) ? Wq : (m == 1) ? Wk : (m == 2) ? Wg : Wm;
    const size_t wo = off0 & 1048575u;
    const float4 a0 = *(const float4*)(Ws + wo);
    const float4 a1 = *(const float4*)(Ws + wo + 4);
    uint4 o;
    o.x = pkbf(a0.x, a0.y); o.y = pkbf(a0.z, a0.w);
    o.z = pkbf(a1.x, a1.y); o.w = pkbf(a1.z, a1.w);
    *(uint4*)(Wb + off0) = o;
  }
}

// ---------------- 256x256 MFMA GEMM, 16 waves (4Mx4N), reg-B + LDS-A ----------------
// Per-wave 64x64 (acc 64 VGPR). A: 32KB double-buffered LDS via global_load_lds
// (1 DMA/thread/tile). B: double-buffered in NAMED register sets b0/b1 (4x16B
// loads/thread/tile, straight from L1/L2-hot weights). __syncthreads() is the
// ONLY sync (vmcnt0+lgkmcnt0+barrier): race-free by the round-4/6 argument;
// prefetch overlaps compute because it issues before the MFMAs.
__global__ __launch_bounds__(1024, 4) void gemm256_kernel(
    const unsigned short* __restrict__ xb, const unsigned short* __restrict__ Wb,
    const float* __restrict__ bg, const float* __restrict__ bm,
    unsigned short* __restrict__ qb, unsigned short* __restrict__ kb,
    unsigned short* __restrict__ gb, unsigned short* __restrict__ mb)
{
  __shared__ __align__(16) unsigned short lds[16384];  // 32 KB: A[2][256x32]
  const int t  = threadIdx.x;            // 0..1023
  const int wv = t >> 6, ln = t & 63;    // 16 waves
  const int wr = wv >> 2, wc = wv & 3;   // 4 (M) x 4 (N)
  const int frow = ln & 15, kc = ln >> 4;

  // bijective XCD swizzle: nwg = 1024, 8 XCDs, 128 blocks per chunk
  const int o  = blockIdx.y * 16 + blockIdx.x;
  const int L  = (o & 7) * 128 + (o >> 3);
  const int bx = L & 15, by = L >> 4;
  const int m0 = by * 256;
  const int n0 = bx * 256;
  const int mat = n0 >> 10;
  const int nc0 = n0 & 1023;

  f32x4 acc[4][4];
  #pragma unroll
  for (int i = 0; i < 4; ++i)
    #pragma unroll
    for (int j = 0; j < 4; ++j) { acc[i][j][0]=0.f; acc[i][j][1]=0.f; acc[i][j][2]=0.f; acc[i][j][3]=0.f; }

  // A staging: thread t -> row t>>2 (0..255), k-chunk t&3; linear LDS dest t*16B
  const int arow = t >> 2;
  const int ach  = (t & 3) << 3;
  auto stageA = [&](int buf, int kt) {
    const unsigned short* ga = xb + (size_t)(m0 + arow) * DD + (kt << 5) + ach;
    __builtin_amdgcn_global_load_lds(
        (const __attribute__((address_space(1))) void*)ga,
        (__attribute__((address_space(3))) void*)((__attribute__((address_space(3))) char*)lds
            + buf * 16384 + t * 16),
        16, 0, 0);
  };

  // B: lane (frow,kc) holds rows n0+wc*64+j*16+frow, k-chunk kc
  const unsigned short* wb0 = Wb + (size_t)(n0 + wc * 64 + frow) * DD + (kc << 3);
  auto loadBv = [&](short8v bd[4], int kt) {
    const int k0 = kt << 5;
    #pragma unroll
    for (int j = 0; j < 4; ++j)
      bd[j] = *(const short8v*)(wb0 + (size_t)(j * 16) * DD + k0);
  };

  short8v b0[4], b1[4];
  stageA(0, 0);
  loadBv(b0, 0);
  __syncthreads();                       // tile 0 in LDS + b0 in regs

  for (int kt2 = 0; kt2 < 16; ++kt2) {
    const int e = kt2 * 2;
    // ---- even tile e: A buf0, B b0; prefetch e+1 -> buf1, b1 ----
    stageA(1, e + 1);                    // e+1 <= 31 always
    loadBv(b1, e + 1);
    {
      short8v a[4];
      #pragma unroll
      for (int i = 0; i < 4; ++i)
        a[i] = *(const short8v*)&lds[(wr * 64 + i * 16 + frow) * 32 + (kc << 3)];
      #pragma unroll
      for (int i = 0; i < 4; ++i)
        #pragma unroll
        for (int j = 0; j < 4; ++j)
          acc[i][j] = __builtin_amdgcn_mfma_f32_16x16x32_bf16(a[i], b0[j], acc[i][j], 0, 0, 0);
    }
    __syncthreads();                     // buf1+b1 ready; all waves done with buf0
    // ---- odd tile e+1: A buf1, B b1; prefetch e+2 -> buf0, b0 ----
    if (kt2 < 15) {
      stageA(0, e + 2);
      loadBv(b0, e + 2);
    }
    {
      short8v a[4];
      #pragma unroll
      for (int i = 0; i < 4; ++i)
        a[i] = *(const short8v*)&lds[8192 + (wr * 64 + i * 16 + frow) * 32 + (kc << 3)];
      #pragma unroll
      for (int i = 0; i < 4; ++i)
        #pragma unroll
        for (int j = 0; j < 4; ++j)
          acc[i][j] = __builtin_amdgcn_mfma_f32_16x16x32_bf16(a[i], b1[j], acc[i][j], 0, 0, 0);
    }
    __syncthreads();                     // buf0+b0 ready; all waves done with buf1
  }

  unsigned short* outp = (mat == 0) ? qb : (mat == 1) ? kb : (mat == 2) ? gb : mb;
  #pragma unroll
  for (int i = 0; i < 4; ++i) {
    #pragma unroll
    for (int j = 0; j < 4; ++j) {
      const int col = nc0 + wc * 64 + j * 16 + frow;
      const float bias = (mat == 2) ? bg[col] : (mat == 3) ? bm[col] : 0.f;
      #pragma unroll
      for (int r = 0; r < 4; ++r) {
        const int row = m0 + wr * 64 + i * 16 + kc * 4 + r;
        float v = acc[i][j][r] + bias;
        if (mat == 3) v = fmaxf(v, 0.0f);
        outp[(size_t)row * DD + col] = f2bf(v);
      }
    }
  }
}

// ---------------- fallback GEMM (ws too small): reg-staged f32->bf16, 128x128 ----
__global__ __launch_bounds__(256) void mfma_gemm_fb(
    const float* __restrict__ x,
    const float* __restrict__ Wq, const float* __restrict__ Wk,
    const float* __restrict__ Wg, const float* __restrict__ Wm,
    const float* __restrict__ bg, const float* __restrict__ bm,
    unsigned short* __restrict__ q_o, unsigned short* __restrict__ k_o,
    unsigned short* __restrict__ g_o, unsigned short* __restrict__ m_o)
{
  __shared__ __align__(16) unsigned short As[128 * 32];
  __shared__ __align__(16) unsigned short Bs[128 * 32];
  const int t  = threadIdx.x;
  const int wv = t >> 6, ln = t & 63;
  const int wr = wv >> 1, wc = wv & 1;
  const int m0 = blockIdx.y * 128;
  const int n0 = blockIdx.x * 128;
  const int mat = n0 >> 10;
  const int nc0 = n0 & 1023;
  const float* __restrict__ Wsrc = (mat == 0) ? Wq : (mat == 1) ? Wk : (mat == 2) ? Wg : Wm;

  f32x4 acc[4][4];
  #pragma unroll
  for (int i = 0; i < 4; ++i)
    #pragma unroll
    for (int j = 0; j < 4; ++j) { acc[i][j][0]=0.f; acc[i][j][1]=0.f; acc[i][j][2]=0.f; acc[i][j][3]=0.f; }

  const int frow = ln & 15, kc = ln >> 4;

  for (int k0 = 0; k0 < DD; k0 += 32) {
    #pragma unroll
    for (int c = 0; c < 2; ++c) {
      const int i = c * 256 + t;
      const int row = i >> 2, colc = i & 3;
      const float* ga = x    + (size_t)(m0 + row) * DD + k0 + (colc << 3);
      const float* gw = Wsrc + (size_t)(nc0 + row) * DD + k0 + (colc << 3);
      const float4 a0 = *(const float4*)ga, a1 = *(const float4*)(ga + 4);
      const float4 b0 = *(const float4*)gw, b1 = *(const float4*)(gw + 4);
      uint4 ao, bo;
      ao.x = pkbf(a0.x, a0.y); ao.y = pkbf(a0.z, a0.w);
      ao.z = pkbf(a1.x, a1.y); ao.w = pkbf(a1.z, a1.w);
      bo.x = pkbf(b0.x, b0.y); bo.y = pkbf(b0.z, b0.w);
      bo.z = pkbf(b1.x, b1.y); bo.w = pkbf(b1.z, b1.w);
      *(uint4*)&As[row * 32 + colc * 8] = ao;
      *(uint4*)&Bs[row * 32 + colc * 8] = bo;
    }
    __syncthreads();
    short8v a[4], b[4];
    #pragma unroll
    for (int i = 0; i < 4; ++i) {
      a[i] = *(const short8v*)&As[(wr * 64 + i * 16 + frow) * 32 + kc * 8];
      b[i] = *(const short8v*)&Bs[(wc * 64 + i * 16 + frow) * 32 + kc * 8];
    }
    #pragma unroll
    for (int i = 0; i < 4; ++i)
      #pragma unroll
      for (int j = 0; j < 4; ++j)
        acc[i][j] = __builtin_amdgcn_mfma_f32_16x16x32_bf16(a[i], b[j], acc[i][j], 0, 0, 0);
    __syncthreads();
  }

  unsigned short* outp = (mat == 0) ? q_o : (mat == 1) ? k_o : (mat == 2) ? g_o : m_o;
  #pragma unroll
  for (int i = 0; i < 4; ++i) {
    #pragma unroll
    for (int j = 0; j < 4; ++j) {
      const int col = nc0 + wc * 64 + j * 16 + frow;
      #pragma unroll
      for (int r = 0; r < 4; ++r) {
        const int row = m0 + wr * 64 + i * 16 + kc * 4 + r;
        float v = acc[i][j][r];
        if (mat == 2) v += bg[col];
        if (mat == 3) v = fmaxf(v + bm[col], 0.0f);
        outp[(size_t)row * DD + col] = f2bf(v);
      }
    }
  }
}

// ---------------- Phase 2 (slim): wave-per-token gate/topk/twist only ----------------
__global__ __launch_bounds__(256) void token_kernel3(
    const unsigned short* __restrict__ qb, const unsigned short* __restrict__ kb,
    const unsigned short* __restrict__ gb, const unsigned short* __restrict__ mb,
    float* __restrict__ craw)
{
  const int wv = threadIdx.x >> 6;
  const int ln = threadIdx.x & 63;
  const int token = blockIdx.x * 4 + wv;
  const int s = token & (SS - 1);
  const size_t rowo = (size_t)token * DD;

  if (s == 0) { if (ln == 0) craw[token] = 0.f; return; }

  unsigned short gbit[16];
  *(uint4*)&gbit[0] = *(const uint4*)(gb + rowo + ln * 16);
  *(uint4*)&gbit[8] = *(const uint4*)(gb + rowo + ln * 16 + 8);
  int ckey[16];
  float asum = 0.f;
  #pragma unroll
  for (int i = 0; i < 16; ++i) {
    const unsigned int b = gbit[i];
    ckey[i] = (b & 0x8000u) ? (int)(b ^ 0xFFFFu) : (int)(b | 0x8000u);
    asum += bf2f(b & 0x7FFFu);
  }
  #pragma unroll
  for (int off = 1; off < 64; off <<= 1) asum += __shfl_xor(asum, off);
  const float strength = tanhf(asum * (1.0f / 1024.0f));
  int kkv = (int)ceilf(strength * 256.0f);
  kkv = min(max(kkv, 1), 1024);

  int lo = 0, hi = 0xFFFF;
  while (lo < hi) {
    const int mid = (lo + hi + 1) >> 1;
    int c = 0;
    #pragma unroll
    for (int i = 0; i < 16; ++i) c += (ckey[i] >= mid);
    #pragma unroll
    for (int off = 1; off < 64; off <<= 1) c += __shfl_xor(c, off);
    if (c >= kkv) lo = mid; else hi = mid - 1;
  }
  const int T = lo;

  int cg = 0, myeq = 0;
  #pragma unroll
  for (int i = 0; i < 16; ++i) { cg += (ckey[i] > T); myeq += (ckey[i] == T); }
  #pragma unroll
  for (int off = 1; off < 64; off <<= 1) cg += __shfl_xor(cg, off);
  int incl = myeq;
  #pragma unroll
  for (int off = 1; off < 64; off <<= 1) {
    const int tt = __shfl_up(incl, off);
    if (ln >= off) incl += tt;
  }
  int ebase = incl - myeq;
  const int keep_eq = kkv - cg;

  unsigned short mB[16], qcB[16], kcB[16], qpB[16], kpB[16];
  *(uint4*)&mB[0]  = *(const uint4*)(mb + rowo + ln * 16);
  *(uint4*)&mB[8]  = *(const uint4*)(mb + rowo + ln * 16 + 8);
  *(uint4*)&qcB[0] = *(const uint4*)(qb + rowo + ln * 16);
  *(uint4*)&qcB[8] = *(const uint4*)(qb + rowo + ln * 16 + 8);
  *(uint4*)&kcB[0] = *(const uint4*)(kb + rowo + ln * 16);
  *(uint4*)&kcB[8] = *(const uint4*)(kb + rowo + ln * 16 + 8);
  *(uint4*)&qpB[0] = *(const uint4*)(qb + rowo - DD + ln * 16);
  *(uint4*)&qpB[8] = *(const uint4*)(qb + rowo - DD + ln * 16 + 8);
  *(uint4*)&kpB[0] = *(const uint4*)(kb + rowo - DD + ln * 16);
  *(uint4*)&kpB[8] = *(const uint4*)(kb + rowo - DD + ln * 16 + 8);

  float accv = 0.f;
  #pragma unroll
  for (int i = 0; i < 16; ++i) {
    const bool kp_ = (ckey[i] > T) || (ckey[i] == T && ebase < keep_eq);
    if (ckey[i] == T) ebase++;
    const unsigned int b = gbit[i];
    const bool gpos = (!(b & 0x8000u)) && (b != 0u);   // g > 0
    if (gpos && kp_) {
      const float tw = bf2f(qpB[i]) * bf2f(kcB[i]) - bf2f(qcB[i]) * bf2f(kpB[i]);
      accv += bf2f(mB[i]) * fabsf(tw);
    }
  }
  #pragma unroll
  for (int off = 1; off < 64; off <<= 1) accv += __shfl_xor(accv, off);
  if (ln == 0) craw[token] = accv * (1.0f / 1024.0f);
}

// ---------------- full token kernel (fallback path only) ----------------
__global__ __launch_bounds__(256) void token_kernel2(
    const float* __restrict__ x, const float* __restrict__ Wc,
    const unsigned short* __restrict__ qb, const unsigned short* __restrict__ kb,
    const unsigned short* __restrict__ gb, const unsigned short* __restrict__ mb,
    float* __restrict__ probs, float* __restrict__ craw)
{
  const int wv = threadIdx.x >> 6;
  const int ln = threadIdx.x & 63;
  const int token = blockIdx.x * 4 + wv;
  const int s = token & (SS - 1);
  const size_t rowo = (size_t)token * DD;

  const float4* x4 = (const float4*)(x + rowo);
  const float4* Wc4 = (const float4*)Wc;
  float4 xv[4];
  #pragma unroll
  for (int e = 0; e < 4; ++e) xv[e] = x4[e * 64 + ln];
  float pj[16];
  #pragma unroll
  for (int j = 0; j < 16; ++j) {
    float a = 0.f;
    #pragma unroll
    for (int e = 0; e < 4; ++e) {
      const float4 w = Wc4[j * 256 + e * 64 + ln];
      a += xv[e].x * w.x + xv[e].y * w.y + xv[e].z * w.z + xv[e].w * w.w;
    }
    pj[j] = a;
  }
  #pragma unroll
  for (int j = 0; j < 16; ++j) {
    #pragma unroll
    for (int off = 1; off < 64; off <<= 1) pj[j] += __shfl_xor(pj[j], off);
  }
  if (ln == 0) {
    float p[16];
    float mx = -3.4e38f;
    #pragma unroll
    for (int j = 0; j < 16; ++j) { p[j] = pj[j] * 10.0f; mx = fmaxf(mx, p[j]); }
    float se = 0.f;
    #pragma unroll
    for (int j = 0; j < 16; ++j) { p[j] = expf(p[j] - mx); se += p[j]; }
    const float inv = 1.0f / se;
    #pragma unroll
    for (int j = 0; j < 16; ++j) p[j] *= inv;
    unsigned int mk = 0;
    for (int it = 0; it < 4; ++it) {
      int bi = 0; float bv = -1.f;
      #pragma unroll
      for (int j = 0; j < 16; ++j)
        if (!((mk >> j) & 1u) && p[j] > bv) { bv = p[j]; bi = j; }
      mk |= 1u << bi;
    }
    float ssum = 0.f;
    #pragma unroll
    for (int j = 0; j < 16; ++j) if ((mk >> j) & 1u) ssum += p[j];
    const float rinv = 1.0f / fmaxf(ssum, 1e-8f);
    #pragma unroll
    for (int j = 0; j < 16; ++j)
      probs[(size_t)token * 16 + j] = ((mk >> j) & 1u) ? p[j] * rinv : 0.f;
  }

  if (s == 0) { if (ln == 0) craw[token] = 0.f; return; }

  unsigned short gbit[16];
  *(uint4*)&gbit[0] = *(const uint4*)(gb + rowo + ln * 16);
  *(uint4*)&gbit[8] = *(const uint4*)(gb + rowo + ln * 16 + 8);
  int ckey[16];
  float asum = 0.f;
  #pragma unroll
  for (int i = 0; i < 16; ++i) {
    const unsigned int b = gbit[i];
    ckey[i] = (b & 0x8000u) ? (int)(b ^ 0xFFFFu) : (int)(b | 0x8000u);
    asum += bf2f(b & 0x7FFFu);
  }
  #pragma unroll
  for (int off = 1; off < 64; off <<= 1) asum += __shfl_xor(asum, off);
  const float strength = tanhf(asum * (1.0f / 1024.0f));
  int kkv = (int)ceilf(strength * 256.0f);
  kkv = min(max(kkv, 1), 1024);

  int lo = 0, hi = 0xFFFF;
  while (lo < hi) {
    const int mid = (lo + hi + 1) >> 1;
    int c = 0;
    #pragma unroll
    for (int i = 0; i < 16; ++i) c += (ckey[i] >= mid);
    #pragma unroll
    for (int off = 1; off < 64; off <<= 1) c += __shfl_xor(c, off);
    if (c >= kkv) lo = mid; else hi = mid - 1;
  }
  const int T = lo;

  int cg = 0, myeq = 0;
  #pragma unroll
  for (int i = 0; i < 16; ++i) { cg += (ckey[i] > T); myeq += (ckey[i] == T); }
  #pragma unroll
  for (int off = 1; off < 64; off <<= 1) cg += __shfl_xor(cg, off);
  int incl = myeq;
  #pragma unroll
  for (int off = 1; off < 64; off <<= 1) {
    const int tt = __shfl_up(incl, off);
    if (ln >= off) incl += tt;
  }
  int ebase = incl - myeq;
  const int keep_eq = kkv - cg;

  unsigned short mB[16], qcB[16], kcB[16], qpB[16], kpB[16];
  *(uint4*)&mB[0]  = *(const uint4*)(mb + rowo + ln * 16);
  *(uint4*)&mB[8]  = *(const uint4*)(mb + rowo + ln * 16 + 8);
  *(uint4*)&qcB[0] = *(const uint4*)(qb + rowo + ln * 16);
  *(uint4*)&qcB[8] = *(const uint4*)(qb + rowo + ln * 16 + 8);
  *(uint4*)&kcB[0] = *(const uint4*)(kb + rowo + ln * 16);
  *(uint4*)&kcB[8] = *(const uint4*)(kb + rowo + ln * 16 + 8);
  *(uint4*)&qpB[0] = *(const uint4*)(qb + rowo - DD + ln * 16);
  *(uint4*)&qpB[8] = *(const uint4*)(qb + rowo - DD + ln * 16 + 8);
  *(uint4*)&kpB[0] = *(const uint4*)(kb + rowo - DD + ln * 16);
  *(uint4*)&kpB[8] = *(const uint4*)(kb + rowo - DD + ln * 16 + 8);

  float accv = 0.f;
  #pragma unroll
  for (int i = 0; i < 16; ++i) {
    const bool kp_ = (ckey[i] > T) || (ckey[i] == T && ebase < keep_eq);
    if (ckey[i] == T) ebase++;
    const unsigned int b = gbit[i];
    const bool gpos = (!(b & 0x8000u)) && (b != 0u);
    if (gpos && kp_) {
      const float tw = bf2f(qpB[i]) * bf2f(kcB[i]) - bf2f(qcB[i]) * bf2f(kpB[i]);
      accv += bf2f(mB[i]) * fabsf(tw);
    }
  }
  #pragma unroll
  for (int off = 1; off < 64; off <<= 1) accv += __shfl_xor(accv, off);
  if (ln == 0) craw[token] = accv * (1.0f / 1024.0f);
}

// ---------------- fused tail: quorum sigmoid + cb shift + budget top-2048 + mix ----
// One block per batch (256 threads). Phase A: all threads compute quorum/cb for 16
// consecutive positions each -> LDS. Phase B: wave 0 runs the exact budget top-k
// (verbatim final_kernel logic) from LDS and writes the output.
__global__ __launch_bounds__(256) void tail_kernel(
    const float* __restrict__ craw, const float* __restrict__ probs,
    float* __restrict__ outp)
{
  __shared__ float qs[SS];
  __shared__ float cs_[SS];
  const int b = blockIdx.x;
  const int t = threadIdx.x;
  const size_t base = (size_t)b * SS;

  #pragma unroll
  for (int i = 0; i < 16; ++i) {
    const int s = t * 16 + i;
    const float c1 = craw[base + s];
    const float c0 = (s > 0) ? craw[base + s - 1] : 0.f;
    const float c2 = (s < SS - 1) ? craw[base + s + 1] : 0.f;
    const float local = (c0 + c1 + c2) / 3.0f;
    qs[s] = 1.0f / (1.0f + expf((0.5f - local) * 10.0f));
    float sh = 0.f;
    if (s > 0) {
      #pragma unroll
      for (int j = 0; j < 16; ++j)
        sh += fabsf(probs[(base + s) * 16 + j] - probs[(base + s - 1) * 16 + j]);
    }
    cs_[s] = 0.5f * sh;
  }
  __syncthreads();

  if (t < 64) {
    const int ln = t;
    float qv[64]; unsigned int key[64];
    #pragma unroll
    for (int i = 0; i < 64; ++i) {
      qv[i] = qs[ln * 64 + i];
      const unsigned int bb = __float_as_uint(qv[i]);
      key[i] = (bb & 0x80000000u) ? ~bb : (bb | 0x80000000u);
    }
    unsigned int lo = 0u, hi = 0xFFFFFFFFu;
    while (lo < hi) {
      const unsigned int mid = (unsigned int)(((unsigned long long)lo + hi + 1ull) >> 1);
      int c = 0;
      #pragma unroll
      for (int i = 0; i < 64; ++i) c += (key[i] >= mid);
      #pragma unroll
      for (int off = 1; off < 64; off <<= 1) c += __shfl_xor(c, off);
      if (c >= BUDGET) lo = mid; else hi = mid - 1;
    }
    const unsigned int T = lo;
    int cg = 0, myeq = 0;
    #pragma unroll
    for (int i = 0; i < 64; ++i) { cg += (key[i] > T); myeq += (key[i] == T); }
    #pragma unroll
    for (int off = 1; off < 64; off <<= 1) cg += __shfl_xor(cg, off);
    int scan = myeq;
    #pragma unroll
    for (int off = 1; off < 64; off <<= 1) {
      const int nsc = __shfl_up(scan, off);
      if (ln >= off) scan += nsc;
    }
    int ebase = scan - myeq;
    const int keep_eq = BUDGET - cg;
    #pragma unroll
    for (int i = 0; i < 64; ++i) {
      const int s = ln * 64 + i;
      const size_t sidx = base + s;
      const bool kp_ = (key[i] > T) || (key[i] == T && ebase < keep_eq);
      if (key[i] == T) ebase++;
      const float q = kp_ ? qv[i] : 0.f;
      outp[sidx] = 0.7f * (craw[sidx] * (0.5f + 0.5f * q)) + 0.3f * cs_[s];
    }
  }
}

extern "C" void kernel_launch(void* const* d_in, const int* in_sizes, int n_in,
                              void* d_out, int out_size, void* d_ws, size_t ws_size,
                              hipStream_t stream)
{
  const float* x  = (const float*)d_in[0];
  const float* Wq = (const float*)d_in[1];
  const float* Wk = (const float*)d_in[2];
  const float* Wg = (const float*)d_in[3];
  const float* bg = (const float*)d_in[4];
  const float* Wm = (const float*)d_in[5];
  const float* bm = (const float*)d_in[6];
  const float* Wc = (const float*)d_in[7];
  float* outp = (float*)d_out;
  char* w = (char*)d_ws;

  const size_t SZ_BF = (size_t)MM * DD * 2;        // 32 MB per bf16 intermediate
  const size_t SMALL_OFF = 4 * SZ_BF;              // 134217728
  const size_t SZ_SMALL = 1048576 + 65536;         // probs + craw

  unsigned short* qb = (unsigned short*)(w);
  unsigned short* kb = (unsigned short*)(w + SZ_BF);
  unsigned short* gb = (unsigned short*)(w + 2 * SZ_BF);
  unsigned short* mb = (unsigned short*)(w + 3 * SZ_BF);
  char* sm = w + SMALL_OFF;
  float* probs  = (float*)(sm);
  float* craw   = (float*)(sm + 1048576);

  const size_t need_mid = SMALL_OFF + SZ_SMALL + SZ_BF + (size_t)4 * 1048576 * 2;

  if (ws_size >= need_mid) {
    unsigned short* xb = (unsigned short*)(sm + SZ_SMALL);
    unsigned short* Wb = xb + (size_t)MM * DD;
    convert2_kernel<<<dim3(4096 + 2048), 256, 0, stream>>>(
        x, Wq, Wk, Wg, Wm, Wc, xb, Wb, probs);
    gemm256_kernel<<<dim3(NTOT / 256, MM / 256), 1024, 0, stream>>>(
        xb, Wb, bg, bm, qb, kb, gb, mb);
    token_kernel3<<<dim3(MM / 4), 256, 0, stream>>>(qb, kb, gb, mb, craw);
  } else {
    mfma_gemm_fb<<<dim3(NTOT / 128, MM / 128), 256, 0, stream>>>(
        x, Wq, Wk, Wg, Wm, bg, bm, qb, kb, gb, mb);
    token_kernel2<<<dim3(MM / 4), 256, 0, stream>>>(x, Wc, qb, kb, gb, mb, probs, craw);
  }
  tail_kernel<<<dim3(BB), 256, 0, stream>>>(craw, probs, outp);
}

// Round 9
// 295.449 us; speedup vs baseline: 1.5386x; 1.5386x over previous
//
#include <hip/hip_runtime.h>
#include <hip/hip_bf16.h>
#include <cstdint>

// Problem constants
#define BB 4
#define SS 4096
#define DD 1024
#define MM (BB * SS)          // 16384 tokens
#define NTOT 4096             // 4 matrices * 1024 output features
#define BUDGET 2048

typedef __attribute__((ext_vector_type(8))) short short8v;   // 8 bf16 (4 VGPR)
typedef __attribute__((ext_vector_type(4))) float f32x4;

__device__ __forceinline__ float bf2f(unsigned int h) {
  return __uint_as_float(h << 16);
}
__device__ __forceinline__ unsigned short f2bf(float f) {
  unsigned int u = __float_as_uint(f);
  u = u + 0x7FFFu + ((u >> 16) & 1u);   // RNE
  return (unsigned short)(u >> 16);
}
__device__ __forceinline__ unsigned int pkbf(float lo, float hi) {
  float2 f; f.x = lo; f.y = hi;
  __hip_bfloat162 h = __float22bfloat162_rn(f);
  return *(unsigned int*)&h;
}

// ---------------- convert2: bf16 copies of x & W-concat + fused codebook probs ----
__global__ __launch_bounds__(256) void convert2_kernel(
    const float* __restrict__ x,
    const float* __restrict__ Wq, const float* __restrict__ Wk,
    const float* __restrict__ Wg, const float* __restrict__ Wm,
    const float* __restrict__ Wc,
    unsigned short* __restrict__ xb, unsigned short* __restrict__ Wb,
    float* __restrict__ probs)
{
  const int blk = blockIdx.x;
  const int t = threadIdx.x;
  if (blk < 4096) {
    const int wv = t >> 6, ln = t & 63;
    const int token = blk * 4 + wv;
    const size_t rowo = (size_t)token * DD;
    const float4* x4 = (const float4*)(x + rowo);
    const float4* Wc4 = (const float4*)Wc;
    float4 xv[4];
    #pragma unroll
    for (int e = 0; e < 4; ++e) xv[e] = x4[e * 64 + ln];
    uint2* xo = (uint2*)(xb + rowo);
    #pragma unroll
    for (int e = 0; e < 4; ++e) {
      uint2 o; o.x = pkbf(xv[e].x, xv[e].y); o.y = pkbf(xv[e].z, xv[e].w);
      xo[e * 64 + ln] = o;
    }
    float pj[16];
    #pragma unroll
    for (int j = 0; j < 16; ++j) {
      float a = 0.f;
      #pragma unroll
      for (int e = 0; e < 4; ++e) {
        const float4 w = Wc4[j * 256 + e * 64 + ln];
        a += xv[e].x * w.x + xv[e].y * w.y + xv[e].z * w.z + xv[e].w * w.w;
      }
      pj[j] = a;
    }
    #pragma unroll
    for (int j = 0; j < 16; ++j) {
      #pragma unroll
      for (int off = 1; off < 64; off <<= 1) pj[j] += __shfl_xor(pj[j], off);
    }
    if (ln == 0) {
      float p[16];
      float mx = -3.4e38f;
      #pragma unroll
      for (int j = 0; j < 16; ++j) { p[j] = pj[j] * 10.0f; mx = fmaxf(mx, p[j]); }
      float se = 0.f;
      #pragma unroll
      for (int j = 0; j < 16; ++j) { p[j] = expf(p[j] - mx); se += p[j]; }
      const float inv = 1.0f / se;
      #pragma unroll
      for (int j = 0; j < 16; ++j) p[j] *= inv;
      unsigned int mk = 0;
      for (int it = 0; it < 4; ++it) {
        int bi = 0; float bv = -1.f;
        #pragma unroll
        for (int j = 0; j < 16; ++j)
          if (!((mk >> j) & 1u) && p[j] > bv) { bv = p[j]; bi = j; }
        mk |= 1u << bi;
      }
      float ssum = 0.f;
      #pragma unroll
      for (int j = 0; j < 16; ++j) if ((mk >> j) & 1u) ssum += p[j];
      const float rinv = 1.0f / fmaxf(ssum, 1e-8f);
      #pragma unroll
      for (int j = 0; j < 16; ++j)
        probs[(size_t)token * 16 + j] = ((mk >> j) & 1u) ? p[j] * rinv : 0.f;
    }
  } else {
    const size_t off0 = (size_t)(blk - 4096) * 2048 + t * 8;
    const int m = (int)(off0 >> 20);
    const float* Ws = (m == 0) ? Wq : (m == 1) ? Wk : (m == 2) ? Wg : Wm;
    const size_t wo = off0 & 1048575u;
    const float4 a0 = *(const float4*)(Ws + wo);
    const float4 a1 = *(const float4*)(Ws + wo + 4);
    uint4 o;
    o.x = pkbf(a0.x, a0.y); o.y = pkbf(a0.z, a0.w);
    o.z = pkbf(a1.x, a1.y); o.w = pkbf(a1.z, a1.w);
    *(uint4*)(Wb + off0) = o;
  }
}

// ---------------- 256x256 MFMA GEMM, 16 waves (4Mx4N), per-wave 64x64 ----------------
// PROVEN round-6 version (155 us, 885 TF; passed validation + graph replay +
// ~100 profiled dispatches). A+B double-buffered in 64 KB LDS via global_load_lds
// (pure-DMA staging: no compiler-tracked register loads mixed with manual vmcnt).
// BK=32, counted vmcnt(2), XCD-swizzled blockIdx.
__global__ __launch_bounds__(1024, 4) void gemm256_kernel(
    const unsigned short* __restrict__ xb, const unsigned short* __restrict__ Wb,
    const float* __restrict__ bg, const float* __restrict__ bm,
    unsigned short* __restrict__ qb, unsigned short* __restrict__ kb,
    unsigned short* __restrict__ gb, unsigned short* __restrict__ mb)
{
  __shared__ __align__(16) unsigned short lds[32768];  // 64 KB
  const int t  = threadIdx.x;            // 0..1023
  const int wv = t >> 6, ln = t & 63;    // 16 waves
  const int wr = wv >> 2, wc = wv & 3;   // 4 (M) x 4 (N)
  const int frow = ln & 15, kc = ln >> 4;

  // bijective XCD swizzle: nwg = 1024, 8 XCDs, 128 blocks per chunk
  const int o  = blockIdx.y * 16 + blockIdx.x;
  const int L  = (o & 7) * 128 + (o >> 3);
  const int bx = L & 15, by = L >> 4;
  const int m0 = by * 256;
  const int n0 = bx * 256;
  const int mat = n0 >> 10;
  const int nc0 = n0 & 1023;

  f32x4 acc[4][4];
  #pragma unroll
  for (int i = 0; i < 4; ++i)
    #pragma unroll
    for (int j = 0; j < 4; ++j) { acc[i][j][0]=0.f; acc[i][j][1]=0.f; acc[i][j][2]=0.f; acc[i][j][3]=0.f; }

  // staging: 2 x global_load_lds(16B) per thread per K-tile (A 16KB + B 16KB)
  // thread t -> row t>>2, slot t&3; source k-chunk swizzled (slot ^ row&3)
  const int grow = t >> 2;
  const int gch  = (((t & 3) ^ ((t >> 2) & 3)) << 3);
  auto stage = [&](int buf, int kt) {
    const int k0 = kt << 5;
    const unsigned short* ga = xb + (size_t)(m0 + grow) * DD + k0 + gch;
    const unsigned short* gw = Wb + (size_t)(n0 + grow) * DD + k0 + gch;
    __builtin_amdgcn_global_load_lds(
        (const __attribute__((address_space(1))) void*)ga,
        (__attribute__((address_space(3))) void*)((__attribute__((address_space(3))) char*)lds
            + buf * 32768 + t * 16),
        16, 0, 0);
    __builtin_amdgcn_global_load_lds(
        (const __attribute__((address_space(1))) void*)gw,
        (__attribute__((address_space(3))) void*)((__attribute__((address_space(3))) char*)lds
            + buf * 32768 + 16384 + t * 16),
        16, 0, 0);
  };

  stage(0, 0);
  const int sl = ((kc ^ (frow & 3)) << 3);   // swizzled read slot (ushorts)

  for (int kt = 0; kt < 32; ++kt) {
    const int cur = kt & 1;
    if (kt < 31) {
      stage(cur ^ 1, kt + 1);                              // 4 outstanding
      asm volatile("s_waitcnt vmcnt(2)" ::: "memory");     // tile kt's 2 done
    } else {
      asm volatile("s_waitcnt vmcnt(0)" ::: "memory");
    }
    __builtin_amdgcn_s_barrier();                          // tile kt fully in LDS
    asm volatile("" ::: "memory");

    short8v a[4], b[4];
    #pragma unroll
    for (int i = 0; i < 4; ++i)
      a[i] = *(const short8v*)&lds[cur * 16384 + (wr * 64 + i * 16 + frow) * 32 + sl];
    #pragma unroll
    for (int j = 0; j < 4; ++j)
      b[j] = *(const short8v*)&lds[cur * 16384 + 8192 + (wc * 64 + j * 16 + frow) * 32 + sl];

    #pragma unroll
    for (int i = 0; i < 4; ++i)
      #pragma unroll
      for (int j = 0; j < 4; ++j)
        acc[i][j] = __builtin_amdgcn_mfma_f32_16x16x32_bf16(a[i], b[j], acc[i][j], 0, 0, 0);

    asm volatile("" ::: "memory");                         // pin ds_reads above
    __builtin_amdgcn_s_barrier();                          // done reading buf[cur]
  }

  unsigned short* outp = (mat == 0) ? qb : (mat == 1) ? kb : (mat == 2) ? gb : mb;
  #pragma unroll
  for (int i = 0; i < 4; ++i) {
    #pragma unroll
    for (int j = 0; j < 4; ++j) {
      const int col = nc0 + wc * 64 + j * 16 + frow;
      const float bias = (mat == 2) ? bg[col] : (mat == 3) ? bm[col] : 0.f;
      #pragma unroll
      for (int r = 0; r < 4; ++r) {
        const int row = m0 + wr * 64 + i * 16 + kc * 4 + r;
        float v = acc[i][j][r] + bias;
        if (mat == 3) v = fmaxf(v, 0.0f);
        outp[(size_t)row * DD + col] = f2bf(v);
      }
    }
  }
}

// ---------------- fallback GEMM (ws too small): reg-staged f32->bf16, 128x128 ----
__global__ __launch_bounds__(256) void mfma_gemm_fb(
    const float* __restrict__ x,
    const float* __restrict__ Wq, const float* __restrict__ Wk,
    const float* __restrict__ Wg, const float* __restrict__ Wm,
    const float* __restrict__ bg, const float* __restrict__ bm,
    unsigned short* __restrict__ q_o, unsigned short* __restrict__ k_o,
    unsigned short* __restrict__ g_o, unsigned short* __restrict__ m_o)
{
  __shared__ __align__(16) unsigned short As[128 * 32];
  __shared__ __align__(16) unsigned short Bs[128 * 32];
  const int t  = threadIdx.x;
  const int wv = t >> 6, ln = t & 63;
  const int wr = wv >> 1, wc = wv & 1;
  const int m0 = blockIdx.y * 128;
  const int n0 = blockIdx.x * 128;
  const int mat = n0 >> 10;
  const int nc0 = n0 & 1023;
  const float* __restrict__ Wsrc = (mat == 0) ? Wq : (mat == 1) ? Wk : (mat == 2) ? Wg : Wm;

  f32x4 acc[4][4];
  #pragma unroll
  for (int i = 0; i < 4; ++i)
    #pragma unroll
    for (int j = 0; j < 4; ++j) { acc[i][j][0]=0.f; acc[i][j][1]=0.f; acc[i][j][2]=0.f; acc[i][j][3]=0.f; }

  const int frow = ln & 15, kc = ln >> 4;

  for (int k0 = 0; k0 < DD; k0 += 32) {
    #pragma unroll
    for (int c = 0; c < 2; ++c) {
      const int i = c * 256 + t;
      const int row = i >> 2, colc = i & 3;
      const float* ga = x    + (size_t)(m0 + row) * DD + k0 + (colc << 3);
      const float* gw = Wsrc + (size_t)(nc0 + row) * DD + k0 + (colc << 3);
      const float4 a0 = *(const float4*)ga, a1 = *(const float4*)(ga + 4);
      const float4 b0 = *(const float4*)gw, b1 = *(const float4*)(gw + 4);
      uint4 ao, bo;
      ao.x = pkbf(a0.x, a0.y); ao.y = pkbf(a0.z, a0.w);
      ao.z = pkbf(a1.x, a1.y); ao.w = pkbf(a1.z, a1.w);
      bo.x = pkbf(b0.x, b0.y); bo.y = pkbf(b0.z, b0.w);
      bo.z = pkbf(b1.x, b1.y); bo.w = pkbf(b1.z, b1.w);
      *(uint4*)&As[row * 32 + colc * 8] = ao;
      *(uint4*)&Bs[row * 32 + colc * 8] = bo;
    }
    __syncthreads();
    short8v a[4], b[4];
    #pragma unroll
    for (int i = 0; i < 4; ++i) {
      a[i] = *(const short8v*)&As[(wr * 64 + i * 16 + frow) * 32 + kc * 8];
      b[i] = *(const short8v*)&Bs[(wc * 64 + i * 16 + frow) * 32 + kc * 8];
    }
    #pragma unroll
    for (int i = 0; i < 4; ++i)
      #pragma unroll
      for (int j = 0; j < 4; ++j)
        acc[i][j] = __builtin_amdgcn_mfma_f32_16x16x32_bf16(a[i], b[j], acc[i][j], 0, 0, 0);
    __syncthreads();
  }

  unsigned short* outp = (mat == 0) ? q_o : (mat == 1) ? k_o : (mat == 2) ? g_o : m_o;
  #pragma unroll
  for (int i = 0; i < 4; ++i) {
    #pragma unroll
    for (int j = 0; j < 4; ++j) {
      const int col = nc0 + wc * 64 + j * 16 + frow;
      #pragma unroll
      for (int r = 0; r < 4; ++r) {
        const int row = m0 + wr * 64 + i * 16 + kc * 4 + r;
        float v = acc[i][j][r];
        if (mat == 2) v += bg[col];
        if (mat == 3) v = fmaxf(v + bm[col], 0.0f);
        outp[(size_t)row * DD + col] = f2bf(v);
      }
    }
  }
}

// ---------------- Phase 2 (slim): wave-per-token gate/topk/twist only ----------------
__global__ __launch_bounds__(256) void token_kernel3(
    const unsigned short* __restrict__ qb, const unsigned short* __restrict__ kb,
    const unsigned short* __restrict__ gb, const unsigned short* __restrict__ mb,
    float* __restrict__ craw)
{
  const int wv = threadIdx.x >> 6;
  const int ln = threadIdx.x & 63;
  const int token = blockIdx.x * 4 + wv;
  const int s = token & (SS - 1);
  const size_t rowo = (size_t)token * DD;

  if (s == 0) { if (ln == 0) craw[token] = 0.f; return; }

  unsigned short gbit[16];
  *(uint4*)&gbit[0] = *(const uint4*)(gb + rowo + ln * 16);
  *(uint4*)&gbit[8] = *(const uint4*)(gb + rowo + ln * 16 + 8);
  int ckey[16];
  float asum = 0.f;
  #pragma unroll
  for (int i = 0; i < 16; ++i) {
    const unsigned int b = gbit[i];
    ckey[i] = (b & 0x8000u) ? (int)(b ^ 0xFFFFu) : (int)(b | 0x8000u);
    asum += bf2f(b & 0x7FFFu);
  }
  #pragma unroll
  for (int off = 1; off < 64; off <<= 1) asum += __shfl_xor(asum, off);
  const float strength = tanhf(asum * (1.0f / 1024.0f));
  int kkv = (int)ceilf(strength * 256.0f);
  kkv = min(max(kkv, 1), 1024);

  int lo = 0, hi = 0xFFFF;
  while (lo < hi) {
    const int mid = (lo + hi + 1) >> 1;
    int c = 0;
    #pragma unroll
    for (int i = 0; i < 16; ++i) c += (ckey[i] >= mid);
    #pragma unroll
    for (int off = 1; off < 64; off <<= 1) c += __shfl_xor(c, off);
    if (c >= kkv) lo = mid; else hi = mid - 1;
  }
  const int T = lo;

  int cg = 0, myeq = 0;
  #pragma unroll
  for (int i = 0; i < 16; ++i) { cg += (ckey[i] > T); myeq += (ckey[i] == T); }
  #pragma unroll
  for (int off = 1; off < 64; off <<= 1) cg += __shfl_xor(cg, off);
  int incl = myeq;
  #pragma unroll
  for (int off = 1; off < 64; off <<= 1) {
    const int tt = __shfl_up(incl, off);
    if (ln >= off) incl += tt;
  }
  int ebase = incl - myeq;
  const int keep_eq = kkv - cg;

  unsigned short mB[16], qcB[16], kcB[16], qpB[16], kpB[16];
  *(uint4*)&mB[0]  = *(const uint4*)(mb + rowo + ln * 16);
  *(uint4*)&mB[8]  = *(const uint4*)(mb + rowo + ln * 16 + 8);
  *(uint4*)&qcB[0] = *(const uint4*)(qb + rowo + ln * 16);
  *(uint4*)&qcB[8] = *(const uint4*)(qb + rowo + ln * 16 + 8);
  *(uint4*)&kcB[0] = *(const uint4*)(kb + rowo + ln * 16);
  *(uint4*)&kcB[8] = *(const uint4*)(kb + rowo + ln * 16 + 8);
  *(uint4*)&qpB[0] = *(const uint4*)(qb + rowo - DD + ln * 16);
  *(uint4*)&qpB[8] = *(const uint4*)(qb + rowo - DD + ln * 16 + 8);
  *(uint4*)&kpB[0] = *(const uint4*)(kb + rowo - DD + ln * 16);
  *(uint4*)&kpB[8] = *(const uint4*)(kb + rowo - DD + ln * 16 + 8);

  float accv = 0.f;
  #pragma unroll
  for (int i = 0; i < 16; ++i) {
    const bool kp_ = (ckey[i] > T) || (ckey[i] == T && ebase < keep_eq);
    if (ckey[i] == T) ebase++;
    const unsigned int b = gbit[i];
    const bool gpos = (!(b & 0x8000u)) && (b != 0u);   // g > 0
    if (gpos && kp_) {
      const float tw = bf2f(qpB[i]) * bf2f(kcB[i]) - bf2f(qcB[i]) * bf2f(kpB[i]);
      accv += bf2f(mB[i]) * fabsf(tw);
    }
  }
  #pragma unroll
  for (int off = 1; off < 64; off <<= 1) accv += __shfl_xor(accv, off);
  if (ln == 0) craw[token] = accv * (1.0f / 1024.0f);
}

// ---------------- full token kernel (fallback path only) ----------------
__global__ __launch_bounds__(256) void token_kernel2(
    const float* __restrict__ x, const float* __restrict__ Wc,
    const unsigned short* __restrict__ qb, const unsigned short* __restrict__ kb,
    const unsigned short* __restrict__ gb, const unsigned short* __restrict__ mb,
    float* __restrict__ probs, float* __restrict__ craw)
{
  const int wv = threadIdx.x >> 6;
  const int ln = threadIdx.x & 63;
  const int token = blockIdx.x * 4 + wv;
  const int s = token & (SS - 1);
  const size_t rowo = (size_t)token * DD;

  const float4* x4 = (const float4*)(x + rowo);
  const float4* Wc4 = (const float4*)Wc;
  float4 xv[4];
  #pragma unroll
  for (int e = 0; e < 4; ++e) xv[e] = x4[e * 64 + ln];
  float pj[16];
  #pragma unroll
  for (int j = 0; j < 16; ++j) {
    float a = 0.f;
    #pragma unroll
    for (int e = 0; e < 4; ++e) {
      const float4 w = Wc4[j * 256 + e * 64 + ln];
      a += xv[e].x * w.x + xv[e].y * w.y + xv[e].z * w.z + xv[e].w * w.w;
    }
    pj[j] = a;
  }
  #pragma unroll
  for (int j = 0; j < 16; ++j) {
    #pragma unroll
    for (int off = 1; off < 64; off <<= 1) pj[j] += __shfl_xor(pj[j], off);
  }
  if (ln == 0) {
    float p[16];
    float mx = -3.4e38f;
    #pragma unroll
    for (int j = 0; j < 16; ++j) { p[j] = pj[j] * 10.0f; mx = fmaxf(mx, p[j]); }
    float se = 0.f;
    #pragma unroll
    for (int j = 0; j < 16; ++j) { p[j] = expf(p[j] - mx); se += p[j]; }
    const float inv = 1.0f / se;
    #pragma unroll
    for (int j = 0; j < 16; ++j) p[j] *= inv;
    unsigned int mk = 0;
    for (int it = 0; it < 4; ++it) {
      int bi = 0; float bv = -1.f;
      #pragma unroll
      for (int j = 0; j < 16; ++j)
        if (!((mk >> j) & 1u) && p[j] > bv) { bv = p[j]; bi = j; }
      mk |= 1u << bi;
    }
    float ssum = 0.f;
    #pragma unroll
    for (int j = 0; j < 16; ++j) if ((mk >> j) & 1u) ssum += p[j];
    const float rinv = 1.0f / fmaxf(ssum, 1e-8f);
    #pragma unroll
    for (int j = 0; j < 16; ++j)
      probs[(size_t)token * 16 + j] = ((mk >> j) & 1u) ? p[j] * rinv : 0.f;
  }

  if (s == 0) { if (ln == 0) craw[token] = 0.f; return; }

  unsigned short gbit[16];
  *(uint4*)&gbit[0] = *(const uint4*)(gb + rowo + ln * 16);
  *(uint4*)&gbit[8] = *(const uint4*)(gb + rowo + ln * 16 + 8);
  int ckey[16];
  float asum = 0.f;
  #pragma unroll
  for (int i = 0; i < 16; ++i) {
    const unsigned int b = gbit[i];
    ckey[i] = (b & 0x8000u) ? (int)(b ^ 0xFFFFu) : (int)(b | 0x8000u);
    asum += bf2f(b & 0x7FFFu);
  }
  #pragma unroll
  for (int off = 1; off < 64; off <<= 1) asum += __shfl_xor(asum, off);
  const float strength = tanhf(asum * (1.0f / 1024.0f));
  int kkv = (int)ceilf(strength * 256.0f);
  kkv = min(max(kkv, 1), 1024);

  int lo = 0, hi = 0xFFFF;
  while (lo < hi) {
    const int mid = (lo + hi + 1) >> 1;
    int c = 0;
    #pragma unroll
    for (int i = 0; i < 16; ++i) c += (ckey[i] >= mid);
    #pragma unroll
    for (int off = 1; off < 64; off <<= 1) c += __shfl_xor(c, off);
    if (c >= kkv) lo = mid; else hi = mid - 1;
  }
  const int T = lo;

  int cg = 0, myeq = 0;
  #pragma unroll
  for (int i = 0; i < 16; ++i) { cg += (ckey[i] > T); myeq += (ckey[i] == T); }
  #pragma unroll
  for (int off = 1; off < 64; off <<= 1) cg += __shfl_xor(cg, off);
  int incl = myeq;
  #pragma unroll
  for (int off = 1; off < 64; off <<= 1) {
    const int tt = __shfl_up(incl, off);
    if (ln >= off) incl += tt;
  }
  int ebase = incl - myeq;
  const int keep_eq = kkv - cg;

  unsigned short mB[16], qcB[16], kcB[16], qpB[16], kpB[16];
  *(uint4*)&mB[0]  = *(const uint4*)(mb + rowo + ln * 16);
  *(uint4*)&mB[8]  = *(const uint4*)(mb + rowo + ln * 16 + 8);
  *(uint4*)&qcB[0] = *(const uint4*)(qb + rowo + ln * 16);
  *(uint4*)&qcB[8] = *(const uint4*)(qb + rowo + ln * 16 + 8);
  *(uint4*)&kcB[0] = *(const uint4*)(kb + rowo + ln * 16);
  *(uint4*)&kcB[8] = *(const uint4*)(kb + rowo + ln * 16 + 8);
  *(uint4*)&qpB[0] = *(const uint4*)(qb + rowo - DD + ln * 16);
  *(uint4*)&qpB[8] = *(const uint4*)(qb + rowo - DD + ln * 16 + 8);
  *(uint4*)&kpB[0] = *(const uint4*)(kb + rowo - DD + ln * 16);
  *(uint4*)&kpB[8] = *(const uint4*)(kb + rowo - DD + ln * 16 + 8);

  float accv = 0.f;
  #pragma unroll
  for (int i = 0; i < 16; ++i) {
    const bool kp_ = (ckey[i] > T) || (ckey[i] == T && ebase < keep_eq);
    if (ckey[i] == T) ebase++;
    const unsigned int b = gbit[i];
    const bool gpos = (!(b & 0x8000u)) && (b != 0u);
    if (gpos && kp_) {
      const float tw = bf2f(qpB[i]) * bf2f(kcB[i]) - bf2f(qcB[i]) * bf2f(kpB[i]);
      accv += bf2f(mB[i]) * fabsf(tw);
    }
  }
  #pragma unroll
  for (int off = 1; off < 64; off <<= 1) accv += __shfl_xor(accv, off);
  if (ln == 0) craw[token] = accv * (1.0f / 1024.0f);
}

// ---------------- fused tail: quorum sigmoid + cb shift + budget top-2048 + mix ----
__global__ __launch_bounds__(256) void tail_kernel(
    const float* __restrict__ craw, const float* __restrict__ probs,
    float* __restrict__ outp)
{
  __shared__ float qs[SS];
  __shared__ float cs_[SS];
  const int b = blockIdx.x;
  const int t = threadIdx.x;
  const size_t base = (size_t)b * SS;

  #pragma unroll
  for (int i = 0; i < 16; ++i) {
    const int s = t * 16 + i;
    const float c1 = craw[base + s];
    const float c0 = (s > 0) ? craw[base + s - 1] : 0.f;
    const float c2 = (s < SS - 1) ? craw[base + s + 1] : 0.f;
    const float local = (c0 + c1 + c2) / 3.0f;
    qs[s] = 1.0f / (1.0f + expf((0.5f - local) * 10.0f));
    float sh = 0.f;
    if (s > 0) {
      #pragma unroll
      for (int j = 0; j < 16; ++j)
        sh += fabsf(probs[(base + s) * 16 + j] - probs[(base + s - 1) * 16 + j]);
    }
    cs_[s] = 0.5f * sh;
  }
  __syncthreads();

  if (t < 64) {
    const int ln = t;
    float qv[64]; unsigned int key[64];
    #pragma unroll
    for (int i = 0; i < 64; ++i) {
      qv[i] = qs[ln * 64 + i];
      const unsigned int bb = __float_as_uint(qv[i]);
      key[i] = (bb & 0x80000000u) ? ~bb : (bb | 0x80000000u);
    }
    unsigned int lo = 0u, hi = 0xFFFFFFFFu;
    while (lo < hi) {
      const unsigned int mid = (unsigned int)(((unsigned long long)lo + hi + 1ull) >> 1);
      int c = 0;
      #pragma unroll
      for (int i = 0; i < 64; ++i) c += (key[i] >= mid);
      #pragma unroll
      for (int off = 1; off < 64; off <<= 1) c += __shfl_xor(c, off);
      if (c >= BUDGET) lo = mid; else hi = mid - 1;
    }
    const unsigned int T = lo;
    int cg = 0, myeq = 0;
    #pragma unroll
    for (int i = 0; i < 64; ++i) { cg += (key[i] > T); myeq += (key[i] == T); }
    #pragma unroll
    for (int off = 1; off < 64; off <<= 1) cg += __shfl_xor(cg, off);
    int scan = myeq;
    #pragma unroll
    for (int off = 1; off < 64; off <<= 1) {
      const int nsc = __shfl_up(scan, off);
      if (ln >= off) scan += nsc;
    }
    int ebase = scan - myeq;
    const int keep_eq = BUDGET - cg;
    #pragma unroll
    for (int i = 0; i < 64; ++i) {
      const int s = ln * 64 + i;
      const size_t sidx = base + s;
      const bool kp_ = (key[i] > T) || (key[i] == T && ebase < keep_eq);
      if (key[i] == T) ebase++;
      const float q = kp_ ? qv[i] : 0.f;
      outp[sidx] = 0.7f * (craw[sidx] * (0.5f + 0.5f * q)) + 0.3f * cs_[s];
    }
  }
}

extern "C" void kernel_launch(void* const* d_in, const int* in_sizes, int n_in,
                              void* d_out, int out_size, void* d_ws, size_t ws_size,
                              hipStream_t stream)
{
  const float* x  = (const float*)d_in[0];
  const float* Wq = (const float*)d_in[1];
  const float* Wk = (const float*)d_in[2];
  const float* Wg = (const float*)d_in[3];
  const float* bg = (const float*)d_in[4];
  const float* Wm = (const float*)d_in[5];
  const float* bm = (const float*)d_in[6];
  const float* Wc = (const float*)d_in[7];
  float* outp = (float*)d_out;
  char* w = (char*)d_ws;

  const size_t SZ_BF = (size_t)MM * DD * 2;        // 32 MB per bf16 intermediate
  const size_t SMALL_OFF = 4 * SZ_BF;              // 134217728
  const size_t SZ_SMALL = 1048576 + 65536;         // probs + craw

  unsigned short* qb = (unsigned short*)(w);
  unsigned short* kb = (unsigned short*)(w + SZ_BF);
  unsigned short* gb = (unsigned short*)(w + 2 * SZ_BF);
  unsigned short* mb = (unsigned short*)(w + 3 * SZ_BF);
  char* sm = w + SMALL_OFF;
  float* probs  = (float*)(sm);
  float* craw   = (float*)(sm + 1048576);

  const size_t need_mid = SMALL_OFF + SZ_SMALL + SZ_BF + (size_t)4 * 1048576 * 2;

  if (ws_size >= need_mid) {
    unsigned short* xb = (unsigned short*)(sm + SZ_SMALL);
    unsigned short* Wb = xb + (size_t)MM * DD;
    convert2_kernel<<<dim3(4096 + 2048), 256, 0, stream>>>(
        x, Wq, Wk, Wg, Wm, Wc, xb, Wb, probs);
    gemm256_kernel<<<dim3(NTOT / 256, MM / 256), 1024, 0, stream>>>(
        xb, Wb, bg, bm, qb, kb, gb, mb);
    token_kernel3<<<dim3(MM / 4), 256, 0, stream>>>(qb, kb, gb, mb, craw);
  } else {
    mfma_gemm_fb<<<dim3(NTOT / 128, MM / 128), 256, 0, stream>>>(
        x, Wq, Wk, Wg, Wm, bg, bm, qb, kb, gb, mb);
    token_kernel2<<<dim3(MM / 4), 256, 0, stream>>>(x, Wc, qb, kb, gb, mb, probs, craw);
  }
  tail_kernel<<<dim3(BB), 256, 0, stream>>>(craw, probs, outp);
}

// Round 10
// 270.591 us; speedup vs baseline: 1.6799x; 1.0919x over previous
//
#include <hip/hip_runtime.h>
#include <hip/hip_bf16.h>
#include <cstdint>

// Problem constants
#define BB 4
#define SS 4096
#define DD 1024
#define MM (BB * SS)          // 16384 tokens
#define NTOT 4096             // 4 matrices * 1024 output features
#define BUDGET 2048

typedef __attribute__((ext_vector_type(8))) short short8v;   // 8 bf16 (4 VGPR)
typedef __attribute__((ext_vector_type(4))) float f32x4;

__device__ __forceinline__ float bf2f(unsigned int h) {
  return __uint_as_float(h << 16);
}
__device__ __forceinline__ unsigned short f2bf(float f) {
  unsigned int u = __float_as_uint(f);
  u = u + 0x7FFFu + ((u >> 16) & 1u);   // RNE
  return (unsigned short)(u >> 16);
}
__device__ __forceinline__ unsigned int pkbf(float lo, float hi) {
  float2 f; f.x = lo; f.y = hi;
  __hip_bfloat162 h = __float22bfloat162_rn(f);
  return *(unsigned int*)&h;
}

// ---------------- convert2: bf16 copies of x & W-concat + fused codebook probs ----
__global__ __launch_bounds__(256) void convert2_kernel(
    const float* __restrict__ x,
    const float* __restrict__ Wq, const float* __restrict__ Wk,
    const float* __restrict__ Wg, const float* __restrict__ Wm,
    const float* __restrict__ Wc,
    unsigned short* __restrict__ xb, unsigned short* __restrict__ Wb,
    float* __restrict__ probs)
{
  const int blk = blockIdx.x;
  const int t = threadIdx.x;
  if (blk < 4096) {
    const int wv = t >> 6, ln = t & 63;
    const int token = blk * 4 + wv;
    const size_t rowo = (size_t)token * DD;
    const float4* x4 = (const float4*)(x + rowo);
    const float4* Wc4 = (const float4*)Wc;
    float4 xv[4];
    #pragma unroll
    for (int e = 0; e < 4; ++e) xv[e] = x4[e * 64 + ln];
    uint2* xo = (uint2*)(xb + rowo);
    #pragma unroll
    for (int e = 0; e < 4; ++e) {
      uint2 o; o.x = pkbf(xv[e].x, xv[e].y); o.y = pkbf(xv[e].z, xv[e].w);
      xo[e * 64 + ln] = o;
    }
    float pj[16];
    #pragma unroll
    for (int j = 0; j < 16; ++j) {
      float a = 0.f;
      #pragma unroll
      for (int e = 0; e < 4; ++e) {
        const float4 w = Wc4[j * 256 + e * 64 + ln];
        a += xv[e].x * w.x + xv[e].y * w.y + xv[e].z * w.z + xv[e].w * w.w;
      }
      pj[j] = a;
    }
    #pragma unroll
    for (int j = 0; j < 16; ++j) {
      #pragma unroll
      for (int off = 1; off < 64; off <<= 1) pj[j] += __shfl_xor(pj[j], off);
    }
    if (ln == 0) {
      float p[16];
      float mx = -3.4e38f;
      #pragma unroll
      for (int j = 0; j < 16; ++j) { p[j] = pj[j] * 10.0f; mx = fmaxf(mx, p[j]); }
      float se = 0.f;
      #pragma unroll
      for (int j = 0; j < 16; ++j) { p[j] = expf(p[j] - mx); se += p[j]; }
      const float inv = 1.0f / se;
      #pragma unroll
      for (int j = 0; j < 16; ++j) p[j] *= inv;
      unsigned int mk = 0;
      for (int it = 0; it < 4; ++it) {
        int bi = 0; float bv = -1.f;
        #pragma unroll
        for (int j = 0; j < 16; ++j)
          if (!((mk >> j) & 1u) && p[j] > bv) { bv = p[j]; bi = j; }
        mk |= 1u << bi;
      }
      float ssum = 0.f;
      #pragma unroll
      for (int j = 0; j < 16; ++j) if ((mk >> j) & 1u) ssum += p[j];
      const float rinv = 1.0f / fmaxf(ssum, 1e-8f);
      #pragma unroll
      for (int j = 0; j < 16; ++j)
        probs[(size_t)token * 16 + j] = ((mk >> j) & 1u) ? p[j] * rinv : 0.f;
    }
  } else {
    const size_t off0 = (size_t)(blk - 4096) * 2048 + t * 8;
    const int m = (int)(off0 >> 20);
    const float* Ws = (m == 0) ? Wq : (m == 1) ? Wk : (m == 2) ? Wg : Wm;
    const size_t wo = off0 & 1048575u;
    const float4 a0 = *(const float4*)(Ws + wo);
    const float4 a1 = *(const float4*)(Ws + wo + 4);
    uint4 o;
    o.x = pkbf(a0.x, a0.y); o.y = pkbf(a0.z, a0.w);
    o.z = pkbf(a1.x, a1.y); o.w = pkbf(a1.z, a1.w);
    *(uint4*)(Wb + off0) = o;
  }
}

// ---------------- 256x256 MFMA GEMM, 16 waves (4Mx4N), BK=64 ----------------
// Round-6 proven structure (pure-DMA staging + counted vmcnt + raw barriers),
// with BK doubled 32->64: 32 MFMAs per barrier-pair (was 16), halving the
// per-dispatch barrier/drain events 64->32. LDS 128 KB (valid on gfx950,
// cf. m201 template), still 1 block/CU -> no occupancy change.
// Both-sides XOR swizzle (rule #21): source chunk sl^(row&7) at staging,
// same XOR on ds_read -> 8-row spread keeps the 128B-stride read ~2-way.
__global__ __launch_bounds__(1024, 4) void gemm256_kernel(
    const unsigned short* __restrict__ xb, const unsigned short* __restrict__ Wb,
    const float* __restrict__ bg, const float* __restrict__ bm,
    unsigned short* __restrict__ qb, unsigned short* __restrict__ kb,
    unsigned short* __restrict__ gb, unsigned short* __restrict__ mb)
{
  __shared__ __align__(16) unsigned short lds[65536];  // 128 KB: [2][A|B][256][64]
  const int t  = threadIdx.x;            // 0..1023
  const int wv = t >> 6, ln = t & 63;    // 16 waves
  const int wr = wv >> 2, wc = wv & 3;   // 4 (M) x 4 (N)
  const int frow = ln & 15, kc = ln >> 4;

  // bijective XCD swizzle: nwg = 1024, 8 XCDs, 128 blocks per chunk
  const int o  = blockIdx.y * 16 + blockIdx.x;
  const int L  = (o & 7) * 128 + (o >> 3);
  const int bx = L & 15, by = L >> 4;
  const int m0 = by * 256;
  const int n0 = bx * 256;
  const int mat = n0 >> 10;
  const int nc0 = n0 & 1023;

  f32x4 acc[4][4];
  #pragma unroll
  for (int i = 0; i < 4; ++i)
    #pragma unroll
    for (int j = 0; j < 4; ++j) { acc[i][j][0]=0.f; acc[i][j][1]=0.f; acc[i][j][2]=0.f; acc[i][j][3]=0.f; }

  // staging: 4 x global_load_lds(16B)/thread per K-tile (A 32KB + B 32KB).
  // dest slot s = i*1024+t (linear, wave-uniform+lane*16); source chunk
  // swizzled: ch = (s&7) ^ (row&7).
  auto stage = [&](int buf, int kt) {
    const int k0 = kt << 6;
    #pragma unroll
    for (int i = 0; i < 2; ++i) {
      const int s   = i * 1024 + t;        // 0..2047 (16B slots)
      const int row = s >> 3;              // 0..255
      const int ch  = (s & 7) ^ (row & 7); // both-sides swizzle
      const unsigned short* ga = xb + (size_t)(m0 + row) * DD + k0 + ch * 8;
      const unsigned short* gw = Wb + (size_t)(n0 + row) * DD + k0 + ch * 8;
      __builtin_amdgcn_global_load_lds(
          (const __attribute__((address_space(1))) void*)ga,
          (__attribute__((address_space(3))) void*)((__attribute__((address_space(3))) char*)lds
              + buf * 65536 + s * 16),
          16, 0, 0);
      __builtin_amdgcn_global_load_lds(
          (const __attribute__((address_space(1))) void*)gw,
          (__attribute__((address_space(3))) void*)((__attribute__((address_space(3))) char*)lds
              + buf * 65536 + 32768 + s * 16),
          16, 0, 0);
    }
  };

  stage(0, 0);   // 4 outstanding

  for (int kt = 0; kt < 16; ++kt) {
    const int cur = kt & 1;
    if (kt < 15) {
      stage(cur ^ 1, kt + 1);                              // 8 outstanding
      asm volatile("s_waitcnt vmcnt(4)" ::: "memory");     // tile kt's 4 done
    } else {
      asm volatile("s_waitcnt vmcnt(0)" ::: "memory");
    }
    __builtin_amdgcn_s_barrier();                          // tile kt fully in LDS
    asm volatile("" ::: "memory");

    #pragma unroll
    for (int kk = 0; kk < 2; ++kk) {
      const int sl = ((kk * 4 + kc) ^ (frow & 7)) << 3;    // swizzled read slot (ushorts)
      short8v a[4], b[4];
      #pragma unroll
      for (int i = 0; i < 4; ++i)
        a[i] = *(const short8v*)&lds[cur * 32768 + (wr * 64 + i * 16 + frow) * 64 + sl];
      #pragma unroll
      for (int j = 0; j < 4; ++j)
        b[j] = *(const short8v*)&lds[cur * 32768 + 16384 + (wc * 64 + j * 16 + frow) * 64 + sl];
      #pragma unroll
      for (int i = 0; i < 4; ++i)
        #pragma unroll
        for (int j = 0; j < 4; ++j)
          acc[i][j] = __builtin_amdgcn_mfma_f32_16x16x32_bf16(a[i], b[j], acc[i][j], 0, 0, 0);
    }

    asm volatile("" ::: "memory");                         // pin ds_reads above
    __builtin_amdgcn_s_barrier();                          // done reading buf[cur]
  }

  unsigned short* outp = (mat == 0) ? qb : (mat == 1) ? kb : (mat == 2) ? gb : mb;
  #pragma unroll
  for (int i = 0; i < 4; ++i) {
    #pragma unroll
    for (int j = 0; j < 4; ++j) {
      const int col = nc0 + wc * 64 + j * 16 + frow;
      const float bias = (mat == 2) ? bg[col] : (mat == 3) ? bm[col] : 0.f;
      #pragma unroll
      for (int r = 0; r < 4; ++r) {
        const int row = m0 + wr * 64 + i * 16 + kc * 4 + r;
        float v = acc[i][j][r] + bias;
        if (mat == 3) v = fmaxf(v, 0.0f);
        outp[(size_t)row * DD + col] = f2bf(v);
      }
    }
  }
}

// ---------------- fallback GEMM (ws too small): reg-staged f32->bf16, 128x128 ----
__global__ __launch_bounds__(256) void mfma_gemm_fb(
    const float* __restrict__ x,
    const float* __restrict__ Wq, const float* __restrict__ Wk,
    const float* __restrict__ Wg, const float* __restrict__ Wm,
    const float* __restrict__ bg, const float* __restrict__ bm,
    unsigned short* __restrict__ q_o, unsigned short* __restrict__ k_o,
    unsigned short* __restrict__ g_o, unsigned short* __restrict__ m_o)
{
  __shared__ __align__(16) unsigned short As[128 * 32];
  __shared__ __align__(16) unsigned short Bs[128 * 32];
  const int t  = threadIdx.x;
  const int wv = t >> 6, ln = t & 63;
  const int wr = wv >> 1, wc = wv & 1;
  const int m0 = blockIdx.y * 128;
  const int n0 = blockIdx.x * 128;
  const int mat = n0 >> 10;
  const int nc0 = n0 & 1023;
  const float* __restrict__ Wsrc = (mat == 0) ? Wq : (mat == 1) ? Wk : (mat == 2) ? Wg : Wm;

  f32x4 acc[4][4];
  #pragma unroll
  for (int i = 0; i < 4; ++i)
    #pragma unroll
    for (int j = 0; j < 4; ++j) { acc[i][j][0]=0.f; acc[i][j][1]=0.f; acc[i][j][2]=0.f; acc[i][j][3]=0.f; }

  const int frow = ln & 15, kc = ln >> 4;

  for (int k0 = 0; k0 < DD; k0 += 32) {
    #pragma unroll
    for (int c = 0; c < 2; ++c) {
      const int i = c * 256 + t;
      const int row = i >> 2, colc = i & 3;
      const float* ga = x    + (size_t)(m0 + row) * DD + k0 + (colc << 3);
      const float* gw = Wsrc + (size_t)(nc0 + row) * DD + k0 + (colc << 3);
      const float4 a0 = *(const float4*)ga, a1 = *(const float4*)(ga + 4);
      const float4 b0 = *(const float4*)gw, b1 = *(const float4*)(gw + 4);
      uint4 ao, bo;
      ao.x = pkbf(a0.x, a0.y); ao.y = pkbf(a0.z, a0.w);
      ao.z = pkbf(a1.x, a1.y); ao.w = pkbf(a1.z, a1.w);
      bo.x = pkbf(b0.x, b0.y); bo.y = pkbf(b0.z, b0.w);
      bo.z = pkbf(b1.x, b1.y); bo.w = pkbf(b1.z, b1.w);
      *(uint4*)&As[row * 32 + colc * 8] = ao;
      *(uint4*)&Bs[row * 32 + colc * 8] = bo;
    }
    __syncthreads();
    short8v a[4], b[4];
    #pragma unroll
    for (int i = 0; i < 4; ++i) {
      a[i] = *(const short8v*)&As[(wr * 64 + i * 16 + frow) * 32 + kc * 8];
      b[i] = *(const short8v*)&Bs[(wc * 64 + i * 16 + frow) * 32 + kc * 8];
    }
    #pragma unroll
    for (int i = 0; i < 4; ++i)
      #pragma unroll
      for (int j = 0; j < 4; ++j)
        acc[i][j] = __builtin_amdgcn_mfma_f32_16x16x32_bf16(a[i], b[j], acc[i][j], 0, 0, 0);
    __syncthreads();
  }

  unsigned short* outp = (mat == 0) ? q_o : (mat == 1) ? k_o : (mat == 2) ? g_o : m_o;
  #pragma unroll
  for (int i = 0; i < 4; ++i) {
    #pragma unroll
    for (int j = 0; j < 4; ++j) {
      const int col = nc0 + wc * 64 + j * 16 + frow;
      #pragma unroll
      for (int r = 0; r < 4; ++r) {
        const int row = m0 + wr * 64 + i * 16 + kc * 4 + r;
        float v = acc[i][j][r];
        if (mat == 2) v += bg[col];
        if (mat == 3) v = fmaxf(v + bm[col], 0.0f);
        outp[(size_t)row * DD + col] = f2bf(v);
      }
    }
  }
}

// ---------------- Phase 2 (slim): wave-per-token gate/topk/twist only ----------------
__global__ __launch_bounds__(256) void token_kernel3(
    const unsigned short* __restrict__ qb, const unsigned short* __restrict__ kb,
    const unsigned short* __restrict__ gb, const unsigned short* __restrict__ mb,
    float* __restrict__ craw)
{
  const int wv = threadIdx.x >> 6;
  const int ln = threadIdx.x & 63;
  const int token = blockIdx.x * 4 + wv;
  const int s = token & (SS - 1);
  const size_t rowo = (size_t)token * DD;

  if (s == 0) { if (ln == 0) craw[token] = 0.f; return; }

  unsigned short gbit[16];
  *(uint4*)&gbit[0] = *(const uint4*)(gb + rowo + ln * 16);
  *(uint4*)&gbit[8] = *(const uint4*)(gb + rowo + ln * 16 + 8);
  int ckey[16];
  float asum = 0.f;
  #pragma unroll
  for (int i = 0; i < 16; ++i) {
    const unsigned int b = gbit[i];
    ckey[i] = (b & 0x8000u) ? (int)(b ^ 0xFFFFu) : (int)(b | 0x8000u);
    asum += bf2f(b & 0x7FFFu);
  }
  #pragma unroll
  for (int off = 1; off < 64; off <<= 1) asum += __shfl_xor(asum, off);
  const float strength = tanhf(asum * (1.0f / 1024.0f));
  int kkv = (int)ceilf(strength * 256.0f);
  kkv = min(max(kkv, 1), 1024);

  int lo = 0, hi = 0xFFFF;
  while (lo < hi) {
    const int mid = (lo + hi + 1) >> 1;
    int c = 0;
    #pragma unroll
    for (int i = 0; i < 16; ++i) c += (ckey[i] >= mid);
    #pragma unroll
    for (int off = 1; off < 64; off <<= 1) c += __shfl_xor(c, off);
    if (c >= kkv) lo = mid; else hi = mid - 1;
  }
  const int T = lo;

  int cg = 0, myeq = 0;
  #pragma unroll
  for (int i = 0; i < 16; ++i) { cg += (ckey[i] > T); myeq += (ckey[i] == T); }
  #pragma unroll
  for (int off = 1; off < 64; off <<= 1) cg += __shfl_xor(cg, off);
  int incl = myeq;
  #pragma unroll
  for (int off = 1; off < 64; off <<= 1) {
    const int tt = __shfl_up(incl, off);
    if (ln >= off) incl += tt;
  }
  int ebase = incl - myeq;
  const int keep_eq = kkv - cg;

  unsigned short mB[16], qcB[16], kcB[16], qpB[16], kpB[16];
  *(uint4*)&mB[0]  = *(const uint4*)(mb + rowo + ln * 16);
  *(uint4*)&mB[8]  = *(const uint4*)(mb + rowo + ln * 16 + 8);
  *(uint4*)&qcB[0] = *(const uint4*)(qb + rowo + ln * 16);
  *(uint4*)&qcB[8] = *(const uint4*)(qb + rowo + ln * 16 + 8);
  *(uint4*)&kcB[0] = *(const uint4*)(kb + rowo + ln * 16);
  *(uint4*)&kcB[8] = *(const uint4*)(kb + rowo + ln * 16 + 8);
  *(uint4*)&qpB[0] = *(const uint4*)(qb + rowo - DD + ln * 16);
  *(uint4*)&qpB[8] = *(const uint4*)(qb + rowo - DD + ln * 16 + 8);
  *(uint4*)&kpB[0] = *(const uint4*)(kb + rowo - DD + ln * 16);
  *(uint4*)&kpB[8] = *(const uint4*)(kb + rowo - DD + ln * 16 + 8);

  float accv = 0.f;
  #pragma unroll
  for (int i = 0; i < 16; ++i) {
    const bool kp_ = (ckey[i] > T) || (ckey[i] == T && ebase < keep_eq);
    if (ckey[i] == T) ebase++;
    const unsigned int b = gbit[i];
    const bool gpos = (!(b & 0x8000u)) && (b != 0u);   // g > 0
    if (gpos && kp_) {
      const float tw = bf2f(qpB[i]) * bf2f(kcB[i]) - bf2f(qcB[i]) * bf2f(kpB[i]);
      accv += bf2f(mB[i]) * fabsf(tw);
    }
  }
  #pragma unroll
  for (int off = 1; off < 64; off <<= 1) accv += __shfl_xor(accv, off);
  if (ln == 0) craw[token] = accv * (1.0f / 1024.0f);
}

// ---------------- full token kernel (fallback path only) ----------------
__global__ __launch_bounds__(256) void token_kernel2(
    const float* __restrict__ x, const float* __restrict__ Wc,
    const unsigned short* __restrict__ qb, const unsigned short* __restrict__ kb,
    const unsigned short* __restrict__ gb, const unsigned short* __restrict__ mb,
    float* __restrict__ probs, float* __restrict__ craw)
{
  const int wv = threadIdx.x >> 6;
  const int ln = threadIdx.x & 63;
  const int token = blockIdx.x * 4 + wv;
  const int s = token & (SS - 1);
  const size_t rowo = (size_t)token * DD;

  const float4* x4 = (const float4*)(x + rowo);
  const float4* Wc4 = (const float4*)Wc;
  float4 xv[4];
  #pragma unroll
  for (int e = 0; e < 4; ++e) xv[e] = x4[e * 64 + ln];
  float pj[16];
  #pragma unroll
  for (int j = 0; j < 16; ++j) {
    float a = 0.f;
    #pragma unroll
    for (int e = 0; e < 4; ++e) {
      const float4 w = Wc4[j * 256 + e * 64 + ln];
      a += xv[e].x * w.x + xv[e].y * w.y + xv[e].z * w.z + xv[e].w * w.w;
    }
    pj[j] = a;
  }
  #pragma unroll
  for (int j = 0; j < 16; ++j) {
    #pragma unroll
    for (int off = 1; off < 64; off <<= 1) pj[j] += __shfl_xor(pj[j], off);
  }
  if (ln == 0) {
    float p[16];
    float mx = -3.4e38f;
    #pragma unroll
    for (int j = 0; j < 16; ++j) { p[j] = pj[j] * 10.0f; mx = fmaxf(mx, p[j]); }
    float se = 0.f;
    #pragma unroll
    for (int j = 0; j < 16; ++j) { p[j] = expf(p[j] - mx); se += p[j]; }
    const float inv = 1.0f / se;
    #pragma unroll
    for (int j = 0; j < 16; ++j) p[j] *= inv;
    unsigned int mk = 0;
    for (int it = 0; it < 4; ++it) {
      int bi = 0; float bv = -1.f;
      #pragma unroll
      for (int j = 0; j < 16; ++j)
        if (!((mk >> j) & 1u) && p[j] > bv) { bv = p[j]; bi = j; }
      mk |= 1u << bi;
    }
    float ssum = 0.f;
    #pragma unroll
    for (int j = 0; j < 16; ++j) if ((mk >> j) & 1u) ssum += p[j];
    const float rinv = 1.0f / fmaxf(ssum, 1e-8f);
    #pragma unroll
    for (int j = 0; j < 16; ++j)
      probs[(size_t)token * 16 + j] = ((mk >> j) & 1u) ? p[j] * rinv : 0.f;
  }

  if (s == 0) { if (ln == 0) craw[token] = 0.f; return; }

  unsigned short gbit[16];
  *(uint4*)&gbit[0] = *(const uint4*)(gb + rowo + ln * 16);
  *(uint4*)&gbit[8] = *(const uint4*)(gb + rowo + ln * 16 + 8);
  int ckey[16];
  float asum = 0.f;
  #pragma unroll
  for (int i = 0; i < 16; ++i) {
    const unsigned int b = gbit[i];
    ckey[i] = (b & 0x8000u) ? (int)(b ^ 0xFFFFu) : (int)(b | 0x8000u);
    asum += bf2f(b & 0x7FFFu);
  }
  #pragma unroll
  for (int off = 1; off < 64; off <<= 1) asum += __shfl_xor(asum, off);
  const float strength = tanhf(asum * (1.0f / 1024.0f));
  int kkv = (int)ceilf(strength * 256.0f);
  kkv = min(max(kkv, 1), 1024);

  int lo = 0, hi = 0xFFFF;
  while (lo < hi) {
    const int mid = (lo + hi + 1) >> 1;
    int c = 0;
    #pragma unroll
    for (int i = 0; i < 16; ++i) c += (ckey[i] >= mid);
    #pragma unroll
    for (int off = 1; off < 64; off <<= 1) c += __shfl_xor(c, off);
    if (c >= kkv) lo = mid; else hi = mid - 1;
  }
  const int T = lo;

  int cg = 0, myeq = 0;
  #pragma unroll
  for (int i = 0; i < 16; ++i) { cg += (ckey[i] > T); myeq += (ckey[i] == T); }
  #pragma unroll
  for (int off = 1; off < 64; off <<= 1) cg += __shfl_xor(cg, off);
  int incl = myeq;
  #pragma unroll
  for (int off = 1; off < 64; off <<= 1) {
    const int tt = __shfl_up(incl, off);
    if (ln >= off) incl += tt;
  }
  int ebase = incl - myeq;
  const int keep_eq = kkv - cg;

  unsigned short mB[16], qcB[16], kcB[16], qpB[16], kpB[16];
  *(uint4*)&mB[0]  = *(const uint4*)(mb + rowo + ln * 16);
  *(uint4*)&mB[8]  = *(const uint4*)(mb + rowo + ln * 16 + 8);
  *(uint4*)&qcB[0] = *(const uint4*)(qb + rowo + ln * 16);
  *(uint4*)&qcB[8] = *(const uint4*)(qb + rowo + ln * 16 + 8);
  *(uint4*)&kcB[0] = *(const uint4*)(kb + rowo + ln * 16);
  *(uint4*)&kcB[8] = *(const uint4*)(kb + rowo + ln * 16 + 8);
  *(uint4*)&qpB[0] = *(const uint4*)(qb + rowo - DD + ln * 16);
  *(uint4*)&qpB[8] = *(const uint4*)(qb + rowo - DD + ln * 16 + 8);
  *(uint4*)&kpB[0] = *(const uint4*)(kb + rowo - DD + ln * 16);
  *(uint4*)&kpB[8] = *(const uint4*)(kb + rowo - DD + ln * 16 + 8);

  float accv = 0.f;
  #pragma unroll
  for (int i = 0; i < 16; ++i) {
    const bool kp_ = (ckey[i] > T) || (ckey[i] == T && ebase < keep_eq);
    if (ckey[i] == T) ebase++;
    const unsigned int b = gbit[i];
    const bool gpos = (!(b & 0x8000u)) && (b != 0u);
    if (gpos && kp_) {
      const float tw = bf2f(qpB[i]) * bf2f(kcB[i]) - bf2f(qcB[i]) * bf2f(kpB[i]);
      accv += bf2f(mB[i]) * fabsf(tw);
    }
  }
  #pragma unroll
  for (int off = 1; off < 64; off <<= 1) accv += __shfl_xor(accv, off);
  if (ln == 0) craw[token] = accv * (1.0f / 1024.0f);
}

// ---------------- Phase 3a: quorum sigmoid + codebook shift score ----------------
__global__ __launch_bounds__(256) void quorum_kernel(
    const float* __restrict__ craw, const float* __restrict__ probs,
    float* __restrict__ quorum, float* __restrict__ cb)
{
  const int idx = blockIdx.x * 256 + threadIdx.x;
  const int s = idx & (SS - 1);
  const float c1 = craw[idx];
  const float c0 = (s > 0) ? craw[idx - 1] : 0.f;
  const float c2 = (s < SS - 1) ? craw[idx + 1] : 0.f;
  const float local = (c0 + c1 + c2) / 3.0f;
  quorum[idx] = 1.0f / (1.0f + expf((0.5f - local) * 10.0f));
  float sh = 0.f;
  if (s > 0) {
    #pragma unroll
    for (int j = 0; j < 16; ++j)
      sh += fabsf(probs[(size_t)idx * 16 + j] - probs[(size_t)(idx - 1) * 16 + j]);
  }
  cb[idx] = 0.5f * sh;
}

// ---------------- Phase 3b: per-batch budget top-2048 + final mix ----------------
__global__ __launch_bounds__(64) void final_kernel(
    const float* __restrict__ craw, const float* __restrict__ quorum,
    const float* __restrict__ cb, float* __restrict__ outp)
{
  const int b = blockIdx.x;
  const int ln = threadIdx.x;
  const size_t base = (size_t)b * SS;
  float qv[64]; unsigned int key[64];
  #pragma unroll
  for (int i = 0; i < 64; ++i) {
    qv[i] = quorum[base + ln * 64 + i];
    const unsigned int bb = __float_as_uint(qv[i]);
    key[i] = (bb & 0x80000000u) ? ~bb : (bb | 0x80000000u);
  }
  unsigned int lo = 0u, hi = 0xFFFFFFFFu;
  while (lo < hi) {
    const unsigned int mid = (unsigned int)(((unsigned long long)lo + hi + 1ull) >> 1);
    int c = 0;
    #pragma unroll
    for (int i = 0; i < 64; ++i) c += (key[i] >= mid);
    #pragma unroll
    for (int off = 1; off < 64; off <<= 1) c += __shfl_xor(c, off);
    if (c >= BUDGET) lo = mid; else hi = mid - 1;
  }
  const unsigned int T = lo;
  int cg = 0, myeq = 0;
  #pragma unroll
  for (int i = 0; i < 64; ++i) { cg += (key[i] > T); myeq += (key[i] == T); }
  #pragma unroll
  for (int off = 1; off < 64; off <<= 1) cg += __shfl_xor(cg, off);
  int scan = myeq;
  #pragma unroll
  for (int off = 1; off < 64; off <<= 1) {
    const int nsc = __shfl_up(scan, off);
    if (ln >= off) scan += nsc;
  }
  int ebase = scan - myeq;
  const int keep_eq = BUDGET - cg;
  #pragma unroll
  for (int i = 0; i < 64; ++i) {
    const size_t sidx = base + (size_t)ln * 64 + i;
    const bool kp_ = (key[i] > T) || (key[i] == T && ebase < keep_eq);
    if (key[i] == T) ebase++;
    const float q = kp_ ? qv[i] : 0.f;
    outp[sidx] = 0.7f * (craw[sidx] * (0.5f + 0.5f * q)) + 0.3f * cb[sidx];
  }
}

extern "C" void kernel_launch(void* const* d_in, const int* in_sizes, int n_in,
                              void* d_out, int out_size, void* d_ws, size_t ws_size,
                              hipStream_t stream)
{
  const float* x  = (const float*)d_in[0];
  const float* Wq = (const float*)d_in[1];
  const float* Wk = (const float*)d_in[2];
  const float* Wg = (const float*)d_in[3];
  const float* bg = (const float*)d_in[4];
  const float* Wm = (const float*)d_in[5];
  const float* bm = (const float*)d_in[6];
  const float* Wc = (const float*)d_in[7];
  float* outp = (float*)d_out;
  char* w = (char*)d_ws;

  const size_t SZ_BF = (size_t)MM * DD * 2;        // 32 MB per bf16 intermediate
  const size_t SMALL_OFF = 4 * SZ_BF;              // 134217728
  const size_t SZ_SMALL = 1048576 + 3 * 65536;     // probs + craw/quorum/cb

  unsigned short* qb = (unsigned short*)(w);
  unsigned short* kb = (unsigned short*)(w + SZ_BF);
  unsigned short* gb = (unsigned short*)(w + 2 * SZ_BF);
  unsigned short* mb = (unsigned short*)(w + 3 * SZ_BF);
  char* sm = w + SMALL_OFF;
  float* probs  = (float*)(sm);
  float* craw   = (float*)(sm + 1048576);
  float* quorum = (float*)(sm + 1048576 + 65536);
  float* cbuf   = (float*)(sm + 1048576 + 2 * 65536);

  const size_t need_mid = SMALL_OFF + SZ_SMALL + SZ_BF + (size_t)4 * 1048576 * 2;

  if (ws_size >= need_mid) {
    unsigned short* xb = (unsigned short*)(sm + SZ_SMALL);
    unsigned short* Wb = xb + (size_t)MM * DD;
    convert2_kernel<<<dim3(4096 + 2048), 256, 0, stream>>>(
        x, Wq, Wk, Wg, Wm, Wc, xb, Wb, probs);
    gemm256_kernel<<<dim3(NTOT / 256, MM / 256), 1024, 0, stream>>>(
        xb, Wb, bg, bm, qb, kb, gb, mb);
    token_kernel3<<<dim3(MM / 4), 256, 0, stream>>>(qb, kb, gb, mb, craw);
  } else {
    mfma_gemm_fb<<<dim3(NTOT / 128, MM / 128), 256, 0, stream>>>(
        x, Wq, Wk, Wg, Wm, bg, bm, qb, kb, gb, mb);
    token_kernel2<<<dim3(MM / 4), 256, 0, stream>>>(x, Wc, qb, kb, gb, mb, probs, craw);
  }
  quorum_kernel<<<dim3(MM / 256), 256, 0, stream>>>(craw, probs, quorum, cbuf);
  final_kernel<<<dim3(BB), 64, 0, stream>>>(craw, quorum, cbuf, outp);
}